// Round 6
// baseline (260.156 us; speedup 1.0000x reference)
//
#include <hip/hip_runtime.h>
#include <math.h>

#define BB 2
#define LL 2048
#define DM 192
#define DI 384
#define DS 16
#define RK 12
#define NROW (BB*LL)      // 4096
#define NCH 64
#define CLEN (LL/NCH)     // 32
#define EQ 64             // padded x_proj output cols (44 -> 64) for quad layout

__device__ __forceinline__ float siluf(float v) { return v / (1.f + __expf(-v)); }

// ---------------- K0: repack weights ----------------
// wq_in : [48][768][4]   wq_in[((kq*768)+c)*4+i] = in_proj_w[c][kq*4+i]
// wt_out: [384][192]     wt_out[k*192+c]         = out_proj_w[c][k]
// wq_xp : [dir][96][64][4] (e>=44 zero)          = x_proj_w[e][kq*4+i]
// wt_dt : [dir][12][384]                          = dt_w[d][j]
#define N_IN  (DM * 2 * DI)            // 147456
#define N_OUT (DI * DM)                // 73728
#define N_XPQ (2 * (DI/4) * EQ * 4)    // 49152
#define N_DT  (2 * RK * DI)            // 9216
#define N_PREP (N_IN + N_OUT + N_XPQ + N_DT)

__global__ __launch_bounds__(256) void k_wprep(
    const float* __restrict__ wip, const float* __restrict__ wop,
    const float* __restrict__ xpwf, const float* __restrict__ xpwb,
    const float* __restrict__ dtwf, const float* __restrict__ dtwb,
    float* __restrict__ wq_in, float* __restrict__ wt_out,
    float* __restrict__ wq_xp, float* __restrict__ wt_dt) {
  int i = blockIdx.x * 256 + threadIdx.x;
  if (i < N_IN) {
    int kq = i / (2 * DI * 4), rem = i % (2 * DI * 4);
    int c = rem / 4, ii = rem % 4;
    wq_in[i] = wip[c * DM + kq * 4 + ii];
  } else if (i < N_IN + N_OUT) {
    int t = i - N_IN;
    int k = t / DM, c = t % DM;
    wt_out[t] = wop[c * DI + k];
  } else if (i < N_IN + N_OUT + N_XPQ) {
    int t = i - N_IN - N_OUT;
    int dir = t / ((DI/4) * EQ * 4), rem = t % ((DI/4) * EQ * 4);
    int kq = rem / (EQ * 4), rem2 = rem % (EQ * 4);
    int e = rem2 / 4, ii = rem2 % 4;
    const float* src = dir ? xpwb : xpwf;
    wq_xp[t] = (e < RK + 2 * DS) ? src[e * DI + kq * 4 + ii] : 0.f;
  } else if (i < N_PREP) {
    int t = i - N_IN - N_OUT - N_XPQ;
    int dir = t / (RK * DI), rem = t % (RK * DI);
    int j = rem / DI, d = rem % DI;
    const float* src = dir ? dtwb : dtwf;
    wt_dt[t] = src[d * RK + j];
  }
}

// ---------------- K1: residual add + RMSNorm ----------------
__global__ __launch_bounds__(256) void k_rmsnorm(
    const float* __restrict__ h, const float* __restrict__ r,
    const float* __restrict__ w, float* __restrict__ res, float* __restrict__ xn) {
  int row = blockIdx.x * 4 + (threadIdx.x >> 6);
  int lane = threadIdx.x & 63;
  const float* hp = h + row * DM;
  const float* rp = r + row * DM;
  float v0 = hp[lane]       + rp[lane];
  float v1 = hp[lane + 64]  + rp[lane + 64];
  float v2 = hp[lane + 128] + rp[lane + 128];
  float ss = v0 * v0 + v1 * v1 + v2 * v2;
  #pragma unroll
  for (int o = 32; o; o >>= 1) ss += __shfl_xor(ss, o);
  float inv = rsqrtf(ss * (1.f / DM) + 1e-5f);
  float* rr = res + row * DM;
  float* xo = xn + row * DM;
  rr[lane] = v0; rr[lane + 64] = v1; rr[lane + 128] = v2;
  xo[lane]       = v0 * inv * w[lane];
  xo[lane + 64]  = v1 * inv * w[lane + 64];
  xo[lane + 128] = v2 * inv * w[lane + 128];
}

// ---------------- K2: in_proj (quad-packed W) ----------------
// grid: (row-tiles 256, 3 col-tiles); each thread one column, 16 rows
__global__ __launch_bounds__(256) void k_inproj(
    const float* __restrict__ xn, const float* __restrict__ wq,
    float* __restrict__ xh, float* __restrict__ z) {
  __shared__ float xs[DM][16];   // [k][r]
  int r0 = blockIdx.x * 16;
  int c = blockIdx.y * 256 + threadIdx.x;
  for (int idx = threadIdx.x; idx < 16 * DM; idx += 256) {
    int r = idx & 15, k = idx >> 4;     // lane-contiguous LDS store
    xs[k][r] = xn[(r0 + r) * DM + k];
  }
  __syncthreads();
  float acc[16];
  #pragma unroll
  for (int i = 0; i < 16; i++) acc[i] = 0.f;
  for (int kq = 0; kq < DM / 4; kq++) {
    float4 wv = *reinterpret_cast<const float4*>(wq + ((size_t)(kq * 2 * DI) + c) * 4);
    float wv4[4] = {wv.x, wv.y, wv.z, wv.w};
    #pragma unroll
    for (int kk = 0; kk < 4; kk++) {
      float w = wv4[kk];
      const float4* xr = reinterpret_cast<const float4*>(&xs[kq * 4 + kk][0]);
      #pragma unroll
      for (int q = 0; q < 4; q++) {
        float4 a = xr[q];
        acc[4*q+0] += w * a.x; acc[4*q+1] += w * a.y;
        acc[4*q+2] += w * a.z; acc[4*q+3] += w * a.w;
      }
    }
  }
  float* dst = (c < DI) ? (xh + c) : (z + (c - DI));
  #pragma unroll
  for (int r2 = 0; r2 < 16; r2++) dst[(r0 + r2) * DI] = acc[r2];
}

// ---------------- K3a: causal depthwise conv + SiLU (both dirs) ----------------
__global__ __launch_bounds__(256) void k_conv(
    const float* __restrict__ xh,
    const float* __restrict__ cwf, const float* __restrict__ cbf,
    const float* __restrict__ cwb, const float* __restrict__ cbb,
    float* __restrict__ xc) {
  int dir = blockIdx.y;
  int g = blockIdx.x * 256 + threadIdx.x;
  int row = g / DI, d = g % DI;     // row = b*L + s (scan order)
  int b = row >> 11, s = row & (LL - 1);
  const float* cw = dir ? cwb : cwf;
  const float* cb = dir ? cbb : cbf;
  float acc = cb[d];
  #pragma unroll
  for (int k = 0; k < 4; k++) {
    int sp = s - 3 + k;
    if (sp >= 0) {
      int mr = b * LL + (dir ? (LL - 1 - sp) : sp);
      acc += cw[d * 4 + k] * xh[mr * DI + d];
    }
  }
  xc[(dir * NROW + row) * DI + d] = siluf(acc);
}

// ---------------- K3b: x_proj (quad-packed W) + dt + B/C ----------------
// 8-row tiles, 128 threads: e = tid&63, rgroup = tid>>6 owns 4 rows
__global__ __launch_bounds__(128) void k_xproj(
    const float* __restrict__ xc,
    const float* __restrict__ wq_xp, const float* __restrict__ wt_dt,
    const float* __restrict__ dtbf, const float* __restrict__ dtbb,
    float* __restrict__ dt, float* __restrict__ Bm, float* __restrict__ Cm) {
  int dir = blockIdx.y;
  int r0 = blockIdx.x * 8;
  const float* wq  = wq_xp + (size_t)dir * (DI/4) * EQ * 4;  // [96][64][4]
  const float* wdt = wt_dt + dir * RK * DI;                   // [j][384]
  const float* dtb = dir ? dtbb : dtbf;
  __shared__ float xs[8][DI];    // row-major (coalesced staging)
  __shared__ float xd[8][EQ];
  for (int idx = threadIdx.x; idx < 8 * DI; idx += 128) {
    int r = idx / DI, k = idx % DI;     // consecutive lanes -> consecutive k
    xs[r][k] = xc[(size_t)(dir * NROW + r0 + r) * DI + k];
  }
  __syncthreads();
  {
    int e  = threadIdx.x & 63;
    int rg = threadIdx.x >> 6;          // 0..1, rows rg*4 .. rg*4+3
    float a0 = 0.f, a1 = 0.f, a2 = 0.f, a3 = 0.f;
    #pragma unroll 2
    for (int kq = 0; kq < DI / 4; kq++) {
      float4 wv = *reinterpret_cast<const float4*>(wq + ((kq << 6) + e) * 4);
      float4 x0 = *reinterpret_cast<const float4*>(&xs[rg * 4 + 0][kq * 4]);
      float4 x1 = *reinterpret_cast<const float4*>(&xs[rg * 4 + 1][kq * 4]);
      float4 x2 = *reinterpret_cast<const float4*>(&xs[rg * 4 + 2][kq * 4]);
      float4 x3 = *reinterpret_cast<const float4*>(&xs[rg * 4 + 3][kq * 4]);
      a0 += wv.x * x0.x + wv.y * x0.y + wv.z * x0.z + wv.w * x0.w;
      a1 += wv.x * x1.x + wv.y * x1.y + wv.z * x1.z + wv.w * x1.w;
      a2 += wv.x * x2.x + wv.y * x2.y + wv.z * x2.z + wv.w * x2.w;
      a3 += wv.x * x3.x + wv.y * x3.y + wv.z * x3.z + wv.w * x3.w;
    }
    xd[rg * 4 + 0][e] = a0;
    xd[rg * 4 + 1][e] = a1;
    xd[rg * 4 + 2][e] = a2;
    xd[rg * 4 + 3][e] = a3;
  }
  __syncthreads();
  for (int o = threadIdx.x; o < 8 * DI; o += 128) {
    int r = o / DI, d2 = o % DI;
    float a = dtb[d2];
    #pragma unroll
    for (int j = 0; j < RK; j++) a += xd[r][j] * wdt[j * DI + d2];
    a = (a > 20.f) ? a : log1pf(__expf(a));
    dt[(size_t)(dir * NROW + r0 + r) * DI + d2] = a;
  }
  for (int o = threadIdx.x; o < 8 * 32; o += 128) {
    int r = o / 32, j = o % 32;
    float v = xd[r][RK + j];
    if (j < DS) Bm[(size_t)(dir * NROW + r0 + r) * DS + j] = v;
    else        Cm[(size_t)(dir * NROW + r0 + r) * DS + (j - DS)] = v;
  }
}

// ---------------- S1: per-chunk local scan aggregates ----------------
__global__ __launch_bounds__(128) void k_scan1(
    const float* __restrict__ dt, const float* __restrict__ xc,
    const float* __restrict__ Bm,
    const float* __restrict__ Alf, const float* __restrict__ Alb,
    float* __restrict__ S, float* __restrict__ P) {
  int zb = blockIdx.z;              // dir*B + b
  int dir = zb >> 1;
  int d = blockIdx.x * 128 + threadIdx.x;
  int c = blockIdx.y;
  const float* Al = dir ? Alb : Alf;
  float Av[DS];
  {
    const float4* ap = reinterpret_cast<const float4*>(Al + d * DS);
    #pragma unroll
    for (int q = 0; q < 4; q++) {
      float4 a = ap[q];
      Av[4*q+0] = -__expf(a.x); Av[4*q+1] = -__expf(a.y);
      Av[4*q+2] = -__expf(a.z); Av[4*q+3] = -__expf(a.w);
    }
  }
  int rowbase = zb * LL + c * CLEN;
  const float4* Bp4 = reinterpret_cast<const float4*>(Bm + (size_t)rowbase * DS);
  float h[DS];
  #pragma unroll
  for (int n = 0; n < DS; n++) h[n] = 0.f;
  float sdt = 0.f;
  float dtv = dt[(size_t)rowbase * DI + d];
  float xv  = xc[(size_t)rowbase * DI + d];
  #pragma unroll 4
  for (int s = 0; s < CLEN; s++) {
    float dtn_ = 0.f, xn_ = 0.f;
    if (s + 1 < CLEN) {
      dtn_ = dt[(size_t)(rowbase + s + 1) * DI + d];
      xn_  = xc[(size_t)(rowbase + s + 1) * DI + d];
    }
    float4 B0 = Bp4[s*4+0], B1 = Bp4[s*4+1], B2 = Bp4[s*4+2], B3 = Bp4[s*4+3];
    float Bv[DS] = {B0.x,B0.y,B0.z,B0.w, B1.x,B1.y,B1.z,B1.w,
                    B2.x,B2.y,B2.z,B2.w, B3.x,B3.y,B3.z,B3.w};
    float dtx = dtv * xv;
    sdt += dtv;
    #pragma unroll
    for (int n = 0; n < DS; n++) {
      float dA = __expf(dtv * Av[n]);
      h[n] = __fmaf_rn(dA, h[n], dtx * Bv[n]);
    }
    dtv = dtn_; xv = xn_;
  }
  size_t base = ((size_t)(zb * NCH + c) * DI + d) * DS;
  float4* Sp = reinterpret_cast<float4*>(S + base);
  float4* Pp = reinterpret_cast<float4*>(P + base);
  #pragma unroll
  for (int q = 0; q < 4; q++) {
    Sp[q] = make_float4(h[4*q+0], h[4*q+1], h[4*q+2], h[4*q+3]);
    Pp[q] = make_float4(__expf(Av[4*q+0]*sdt), __expf(Av[4*q+1]*sdt),
                        __expf(Av[4*q+2]*sdt), __expf(Av[4*q+3]*sdt));
  }
}

// ---------------- S2: combine carries across chunks (in-place: S -> Hin) ----------------
__global__ __launch_bounds__(256) void k_scan2(
    float* __restrict__ S, const float* __restrict__ P) {
  int g = blockIdx.x * 256 + threadIdx.x;   // 24576 chains
  int zb = g / (DI * DS);
  int rem = g % (DI * DS);
  const int stride = DI * DS;
  size_t base = (size_t)zb * NCH * stride + rem;
  float carry = 0.f;
  for (int c0 = 0; c0 < NCH; c0 += 8) {
    float p8[8], s8[8];
    #pragma unroll
    for (int j = 0; j < 8; j++) {
      p8[j] = P[base + (size_t)(c0 + j) * stride];
      s8[j] = S[base + (size_t)(c0 + j) * stride];
    }
    #pragma unroll
    for (int j = 0; j < 8; j++) {
      S[base + (size_t)(c0 + j) * stride] = carry;      // Hin for chunk c0+j
      carry = __fmaf_rn(p8[j], carry, s8[j]);
    }
  }
}

// ---------------- S3: final per-chunk scan + y ----------------
__global__ __launch_bounds__(128) void k_scan3(
    const float* __restrict__ dt, const float* __restrict__ xc,
    const float* __restrict__ Bm, const float* __restrict__ Cm,
    const float* __restrict__ z, const float* __restrict__ Hin,
    const float* __restrict__ Alf, const float* __restrict__ Alb,
    const float* __restrict__ Df, const float* __restrict__ Db,
    float* __restrict__ y) {
  int zb = blockIdx.z;
  int dir = zb >> 1, b = zb & 1;
  int d = blockIdx.x * 128 + threadIdx.x;
  int c = blockIdx.y;
  const float* Al = dir ? Alb : Alf;
  const float* Dp = dir ? Db : Df;
  float Av[DS];
  {
    const float4* ap = reinterpret_cast<const float4*>(Al + d * DS);
    #pragma unroll
    for (int q = 0; q < 4; q++) {
      float4 a = ap[q];
      Av[4*q+0] = -__expf(a.x); Av[4*q+1] = -__expf(a.y);
      Av[4*q+2] = -__expf(a.z); Av[4*q+3] = -__expf(a.w);
    }
  }
  float Dv = Dp[d];
  int rowbase = zb * LL + c * CLEN;
  const float4* Bp4 = reinterpret_cast<const float4*>(Bm + (size_t)rowbase * DS);
  const float4* Cp4 = reinterpret_cast<const float4*>(Cm + (size_t)rowbase * DS);
  size_t base = ((size_t)(zb * NCH + c) * DI + d) * DS;
  float h[DS];
  {
    const float4* hp = reinterpret_cast<const float4*>(Hin + base);
    #pragma unroll
    for (int q = 0; q < 4; q++) {
      float4 a = hp[q];
      h[4*q+0] = a.x; h[4*q+1] = a.y; h[4*q+2] = a.z; h[4*q+3] = a.w;
    }
  }
  float dtv = dt[(size_t)rowbase * DI + d];
  float xv  = xc[(size_t)rowbase * DI + d];
  #pragma unroll 4
  for (int s = 0; s < CLEN; s++) {
    float dtn_ = 0.f, xn_ = 0.f;
    if (s + 1 < CLEN) {
      dtn_ = dt[(size_t)(rowbase + s + 1) * DI + d];
      xn_  = xc[(size_t)(rowbase + s + 1) * DI + d];
    }
    float4 B0 = Bp4[s*4+0], B1 = Bp4[s*4+1], B2 = Bp4[s*4+2], B3 = Bp4[s*4+3];
    float Bv[DS] = {B0.x,B0.y,B0.z,B0.w, B1.x,B1.y,B1.z,B1.w,
                    B2.x,B2.y,B2.z,B2.w, B3.x,B3.y,B3.z,B3.w};
    float4 C0 = Cp4[s*4+0], C1 = Cp4[s*4+1], C2 = Cp4[s*4+2], C3 = Cp4[s*4+3];
    float Cv[DS] = {C0.x,C0.y,C0.z,C0.w, C1.x,C1.y,C1.z,C1.w,
                    C2.x,C2.y,C2.z,C2.w, C3.x,C3.y,C3.z,C3.w};
    float dtx = dtv * xv;
    float acc = xv * Dv;
    #pragma unroll
    for (int n = 0; n < DS; n++) {
      float dA = __expf(dtv * Av[n]);
      h[n] = __fmaf_rn(dA, h[n], dtx * Bv[n]);
      acc = __fmaf_rn(h[n], Cv[n], acc);
    }
    int sg = c * CLEN + s;
    int mr = b * LL + (dir ? (LL - 1 - sg) : sg);
    float zv = z[(size_t)mr * DI + d];
    y[(size_t)(rowbase + s) * DI + d] = acc * siluf(zv);
    dtv = dtn_; xv = xn_;
  }
}

// ---------------- K5: out = (y_f + rev(y_b)) @ out_proj^T (transposed W) ----------------
__global__ __launch_bounds__(192) void k_outproj(
    const float* __restrict__ y, const float* __restrict__ wt,
    float* __restrict__ out) {
  __shared__ float ys[DI][8];     // [k][r]
  int r0 = blockIdx.x * 8;        // memory-order rows
  for (int idx = threadIdx.x; idx < 8 * DI; idx += 192) {
    int r = idx & 7, k = idx >> 3;    // lane-contiguous LDS store
    int row = r0 + r;
    int b = row >> 11, l = row & (LL - 1);
    float vf = y[(size_t)(b * LL + l) * DI + k];
    float vb = y[(size_t)((2 + b) * LL + (LL - 1 - l)) * DI + k];
    ys[k][r] = vf + vb;
  }
  __syncthreads();
  int c = threadIdx.x;            // 192 threads = 192 output cols
  const float* wc = wt + c;       // stride 192 along k, coalesced across lanes
  float acc[8];
  #pragma unroll
  for (int i = 0; i < 8; i++) acc[i] = 0.f;
  for (int k = 0; k < DI; k += 4) {
    float w0 = wc[(k+0) * DM];
    float w1 = wc[(k+1) * DM];
    float w2 = wc[(k+2) * DM];
    float w3 = wc[(k+3) * DM];
    float wv4[4] = {w0, w1, w2, w3};
    #pragma unroll
    for (int kk = 0; kk < 4; kk++) {
      float wv = wv4[kk];
      const float4* xr = reinterpret_cast<const float4*>(&ys[k + kk][0]);
      float4 a0 = xr[0], a1 = xr[1];
      acc[0] += wv * a0.x; acc[1] += wv * a0.y;
      acc[2] += wv * a0.z; acc[3] += wv * a0.w;
      acc[4] += wv * a1.x; acc[5] += wv * a1.y;
      acc[6] += wv * a1.z; acc[7] += wv * a1.w;
    }
  }
  #pragma unroll
  for (int r2 = 0; r2 < 8; r2++) out[(r0 + r2) * DM + c] = acc[r2];
}

extern "C" void kernel_launch(void* const* d_in, const int* in_sizes, int n_in,
                              void* d_out, int out_size, void* d_ws, size_t ws_size,
                              hipStream_t stream) {
  const float* hid  = (const float*)d_in[0];
  const float* res  = (const float*)d_in[1];
  const float* nw   = (const float*)d_in[2];
  const float* wip  = (const float*)d_in[3];
  const float* wop  = (const float*)d_in[4];
  const float* cwf  = (const float*)d_in[5];
  const float* cbf  = (const float*)d_in[6];
  const float* xpwf = (const float*)d_in[7];
  const float* dtwf = (const float*)d_in[8];
  const float* dtbf = (const float*)d_in[9];
  const float* Alf  = (const float*)d_in[10];
  const float* Df   = (const float*)d_in[11];
  const float* cwb  = (const float*)d_in[12];
  const float* cbb  = (const float*)d_in[13];
  const float* xpwb = (const float*)d_in[14];
  const float* dtwb = (const float*)d_in[15];
  const float* dtbb = (const float*)d_in[16];
  const float* Alb  = (const float*)d_in[17];
  const float* Db   = (const float*)d_in[18];

  float* out_p  = (float*)d_out;                  // (B,L,192)
  float* resid  = out_p + NROW * DM;              // (B,L,192)

  float* ws = (float*)d_ws;
  float* xn  = ws;                       // 786432
  float* xh  = xn  + NROW * DM;          // 1572864
  float* zz  = xh  + NROW * DI;          // 1572864
  float* xc  = zz  + NROW * DI;          // 2*1572864
  float* dt  = xc  + 2 * NROW * DI;      // 2*1572864
  float* Bm  = dt  + 2 * NROW * DI;      // 2*65536
  float* Cm  = Bm  + 2 * NROW * DS;      // 2*65536
  float* yy  = Cm  + 2 * NROW * DS;      // 2*1572864
  float* S   = yy  + 2 * NROW * DI;      // 1572864
  float* P   = S   + 2 * BB * NCH * DI * DS;  // 1572864
  float* wq_in  = P     + 2 * BB * NCH * DI * DS;
  float* wt_out = wq_in  + N_IN;
  float* wq_xp  = wt_out + N_OUT;
  float* wt_dt  = wq_xp  + N_XPQ;

  k_wprep<<<(N_PREP + 255) / 256, 256, 0, stream>>>(wip, wop, xpwf, xpwb, dtwf, dtwb,
                                                    wq_in, wt_out, wq_xp, wt_dt);
  k_rmsnorm<<<NROW / 4, 256, 0, stream>>>(hid, res, nw, resid, xn);
  k_inproj<<<dim3(NROW / 16, 3), 256, 0, stream>>>(xn, wq_in, xh, zz);
  k_conv<<<dim3(NROW * DI / 256, 2), 256, 0, stream>>>(xh, cwf, cbf, cwb, cbb, xc);
  k_xproj<<<dim3(NROW / 8, 2), 128, 0, stream>>>(xc, wq_xp, wt_dt, dtbf, dtbb,
                                                 dt, Bm, Cm);
  k_scan1<<<dim3(DI / 128, NCH, 2 * BB), 128, 0, stream>>>(dt, xc, Bm, Alf, Alb, S, P);
  k_scan2<<<(2 * BB * DI * DS) / 256, 256, 0, stream>>>(S, P);
  k_scan3<<<dim3(DI / 128, NCH, 2 * BB), 128, 0, stream>>>(dt, xc, Bm, Cm, zz, S,
                                                           Alf, Alb, Df, Db, yy);
  k_outproj<<<NROW / 8, 192, 0, stream>>>(yy, wt_out, out_p);
}

// Round 7
// 235.457 us; speedup vs baseline: 1.1049x; 1.1049x over previous
//
#include <hip/hip_runtime.h>
#include <math.h>

#define BB 2
#define LL 2048
#define DM 192
#define DI 384
#define DS 16
#define RK 12
#define NROW (BB*LL)      // 4096
#define NCH 64
#define CLEN (LL/NCH)     // 32

typedef __attribute__((ext_vector_type(8))) short bf16x8;
typedef __attribute__((ext_vector_type(4))) float f32x4;

__device__ __forceinline__ float siluf(float v) { return v / (1.f + __expf(-v)); }

__device__ __forceinline__ unsigned short f2bf(float f) {
  unsigned int x = __float_as_uint(f);
  unsigned int r = (x + 0x7fffu + ((x >> 16) & 1u)) >> 16;
  return (unsigned short)r;
}

// ---------------- K0: pack weights into MFMA fragment order (bf16) ----------
// bin : [6 ks][48 ng][64 l][8 j]  = bf16(in_proj_w[c][k]), c=ng*16+(l&15), k=ks*32+(l>>4)*8+j
// bout: [12][12][64][8]           = bf16(out_proj_w[c][k])
// bxp : [dir][12][4][64][8]       = bf16(x_proj_w[e][k]) (e>=44 -> 0)
// wdt : [dir][12][384] f32        = dt_w[d][j]
#define N_BFIN  (6*48*512)      // 147456
#define N_BFOUT (12*12*512)     // 73728
#define N_BFXP  (2*12*4*512)    // 49152
#define N_DT    (2*RK*DI)       // 9216
#define N_PREP  (N_BFIN + N_BFOUT + N_BFXP + N_DT)

__global__ __launch_bounds__(256) void k_wprep(
    const float* __restrict__ wip, const float* __restrict__ wop,
    const float* __restrict__ xpwf, const float* __restrict__ xpwb,
    const float* __restrict__ dtwf, const float* __restrict__ dtwb,
    unsigned short* __restrict__ bin, unsigned short* __restrict__ bout,
    unsigned short* __restrict__ bxp, float* __restrict__ wdt) {
  int i = blockIdx.x * 256 + threadIdx.x;
  if (i < N_BFIN) {
    int j = i & 7, l = (i >> 3) & 63, ng = (i >> 9) % 48, ks = i / (48 * 512);
    int k = ks * 32 + (l >> 4) * 8 + j, c = ng * 16 + (l & 15);
    bin[i] = f2bf(wip[c * DM + k]);
  } else if (i < N_BFIN + N_BFOUT) {
    int t = i - N_BFIN;
    int j = t & 7, l = (t >> 3) & 63, ng = (t >> 9) % 12, ks = t / (12 * 512);
    int k = ks * 32 + (l >> 4) * 8 + j, c = ng * 16 + (l & 15);
    bout[t] = f2bf(wop[c * DI + k]);
  } else if (i < N_BFIN + N_BFOUT + N_BFXP) {
    int t = i - N_BFIN - N_BFOUT;
    int j = t & 7, l = (t >> 3) & 63, ng = (t >> 9) & 3, ks = (t >> 11) % 12;
    int dir = t / (12 * 4 * 512);
    int k = ks * 32 + (l >> 4) * 8 + j, e = ng * 16 + (l & 15);
    const float* src = dir ? xpwb : xpwf;
    bxp[t] = (e < RK + 2 * DS) ? f2bf(src[e * DI + k]) : (unsigned short)0;
  } else if (i < N_PREP) {
    int t = i - N_BFIN - N_BFOUT - N_BFXP;
    int dir = t / (RK * DI), rem = t % (RK * DI);
    int j = rem / DI, d = rem % DI;
    const float* src = dir ? dtwb : dtwf;
    wdt[t] = src[d * RK + j];
  }
}

// ---------------- K1: residual add + RMSNorm -> bf16 xnb ----------------
__global__ __launch_bounds__(256) void k_rmsnorm(
    const float* __restrict__ h, const float* __restrict__ r,
    const float* __restrict__ w, float* __restrict__ res,
    unsigned short* __restrict__ xnb) {
  int row = blockIdx.x * 4 + (threadIdx.x >> 6);
  int lane = threadIdx.x & 63;
  const float* hp = h + row * DM;
  const float* rp = r + row * DM;
  float v0 = hp[lane]       + rp[lane];
  float v1 = hp[lane + 64]  + rp[lane + 64];
  float v2 = hp[lane + 128] + rp[lane + 128];
  float ss = v0 * v0 + v1 * v1 + v2 * v2;
  #pragma unroll
  for (int o = 32; o; o >>= 1) ss += __shfl_xor(ss, o);
  float inv = rsqrtf(ss * (1.f / DM) + 1e-5f);
  float* rr = res + row * DM;
  unsigned short* xo = xnb + row * DM;
  rr[lane] = v0; rr[lane + 64] = v1; rr[lane + 128] = v2;
  xo[lane]       = f2bf(v0 * inv * w[lane]);
  xo[lane + 64]  = f2bf(v1 * inv * w[lane + 64]);
  xo[lane + 128] = f2bf(v2 * inv * w[lane + 128]);
}

// ---------------- K2: in_proj via MFMA ----------------
// block 256 = 4 waves; tile 16 rows x 768 cols; wave w covers ng = w*12..w*12+11
__global__ __launch_bounds__(256) void k_inproj(
    const unsigned short* __restrict__ xnb, const unsigned short* __restrict__ bin,
    float* __restrict__ xh, float* __restrict__ z) {
  int l = threadIdx.x & 63, w = threadIdx.x >> 6;
  int row0 = blockIdx.x * 16;
  const unsigned short* arow = xnb + (size_t)(row0 + (l & 15)) * DM + ((l >> 4) * 8);
  f32x4 acc[12];
  #pragma unroll
  for (int g = 0; g < 12; g++) acc[g] = (f32x4){0.f, 0.f, 0.f, 0.f};
  #pragma unroll
  for (int ks = 0; ks < 6; ks++) {
    bf16x8 a = *reinterpret_cast<const bf16x8*>(arow + ks * 32);
    #pragma unroll
    for (int g = 0; g < 12; g++) {
      int ng = w * 12 + g;
      bf16x8 b = *reinterpret_cast<const bf16x8*>(bin + ((size_t)(ks * 48 + ng) * 64 + l) * 8);
      acc[g] = __builtin_amdgcn_mfma_f32_16x16x32_bf16(a, b, acc[g], 0, 0, 0);
    }
  }
  int rbase = row0 + (l >> 4) * 4;
  #pragma unroll
  for (int g = 0; g < 12; g++) {
    int col = (w * 12 + g) * 16 + (l & 15);
    float* dst = (col < DI) ? (xh + col) : (z + (col - DI));
    #pragma unroll
    for (int r = 0; r < 4; r++) dst[(size_t)(rbase + r) * DI] = acc[g][r];
  }
}

// ---------------- K3a: causal depthwise conv + SiLU -> f32 xc + bf16 xcb ----
__global__ __launch_bounds__(256) void k_conv(
    const float* __restrict__ xh,
    const float* __restrict__ cwf, const float* __restrict__ cbf,
    const float* __restrict__ cwb, const float* __restrict__ cbb,
    float* __restrict__ xc, unsigned short* __restrict__ xcb) {
  int dir = blockIdx.y;
  int g = blockIdx.x * 256 + threadIdx.x;
  int row = g / DI, d = g % DI;
  int b = row >> 11, s = row & (LL - 1);
  const float* cw = dir ? cwb : cwf;
  const float* cb = dir ? cbb : cbf;
  float acc = cb[d];
  #pragma unroll
  for (int k = 0; k < 4; k++) {
    int sp = s - 3 + k;
    if (sp >= 0) {
      int mr = b * LL + (dir ? (LL - 1 - sp) : sp);
      acc += cw[d * 4 + k] * xh[(size_t)mr * DI + d];
    }
  }
  float v = siluf(acc);
  size_t idx = (size_t)(dir * NROW + row) * DI + d;
  xc[idx] = v;
  xcb[idx] = f2bf(v);
}

// ---------------- K3b-1: x_proj GEMM via MFMA -> xdbl[8192][64] f32 --------
__global__ __launch_bounds__(64) void k_xpmm(
    const unsigned short* __restrict__ xcb, const unsigned short* __restrict__ bxp,
    float* __restrict__ xdbl) {
  int l = threadIdx.x;
  int dir = blockIdx.y;
  int row0 = blockIdx.x * 16;
  const unsigned short* arow = xcb + (size_t)(dir * NROW + row0 + (l & 15)) * DI + ((l >> 4) * 8);
  const unsigned short* wb = bxp + (size_t)dir * 12 * 4 * 512;
  f32x4 acc[4];
  #pragma unroll
  for (int g = 0; g < 4; g++) acc[g] = (f32x4){0.f, 0.f, 0.f, 0.f};
  #pragma unroll
  for (int ks = 0; ks < 12; ks++) {
    bf16x8 a = *reinterpret_cast<const bf16x8*>(arow + ks * 32);
    #pragma unroll
    for (int g = 0; g < 4; g++) {
      bf16x8 b = *reinterpret_cast<const bf16x8*>(wb + ((size_t)(ks * 4 + g) * 64 + l) * 8);
      acc[g] = __builtin_amdgcn_mfma_f32_16x16x32_bf16(a, b, acc[g], 0, 0, 0);
    }
  }
  int rbase = row0 + (l >> 4) * 4;
  #pragma unroll
  for (int g = 0; g < 4; g++) {
    int col = g * 16 + (l & 15);
    #pragma unroll
    for (int r = 0; r < 4; r++)
      xdbl[(size_t)(dir * NROW + rbase + r) * 64 + col] = acc[g][r];
  }
}

// ---------------- K3b-2: dt = softplus(xdbl[:,:12] @ wdt + b); B,C extract --
__global__ __launch_bounds__(128) void k_dtbc(
    const float* __restrict__ xdbl, const float* __restrict__ wdt_all,
    const float* __restrict__ dtbf, const float* __restrict__ dtbb,
    float* __restrict__ dt, float* __restrict__ Bm, float* __restrict__ Cm) {
  int row = blockIdx.x;             // 0..8191 (dir*4096 + r)
  int dir = row >> 12;
  const float* xr = xdbl + (size_t)row * 64;
  float xj[RK];
  #pragma unroll
  for (int j = 0; j < RK; j++) xj[j] = xr[j];
  const float* wdt = wdt_all + dir * RK * DI;
  const float* dtb = dir ? dtbb : dtbf;
  int t = threadIdx.x;
  #pragma unroll
  for (int it = 0; it < 3; it++) {
    int d = it * 128 + t;
    float a = dtb[d];
    #pragma unroll
    for (int j = 0; j < RK; j++) a = __fmaf_rn(xj[j], wdt[j * DI + d], a);
    a = (a > 20.f) ? a : log1pf(__expf(a));
    dt[(size_t)row * DI + d] = a;
  }
  if (t < 32) {
    float v = xr[RK + t];
    if (t < DS) Bm[(size_t)row * DS + t] = v;
    else        Cm[(size_t)row * DS + (t - DS)] = v;
  }
}

// ---------------- S1: per-chunk local scan aggregates ----------------
__global__ __launch_bounds__(128) void k_scan1(
    const float* __restrict__ dt, const float* __restrict__ xc,
    const float* __restrict__ Bm,
    const float* __restrict__ Alf, const float* __restrict__ Alb,
    float* __restrict__ S, float* __restrict__ P) {
  int zb = blockIdx.z;
  int dir = zb >> 1;
  int d = blockIdx.x * 128 + threadIdx.x;
  int c = blockIdx.y;
  const float* Al = dir ? Alb : Alf;
  float Av[DS];
  {
    const float4* ap = reinterpret_cast<const float4*>(Al + d * DS);
    #pragma unroll
    for (int q = 0; q < 4; q++) {
      float4 a = ap[q];
      Av[4*q+0] = -__expf(a.x); Av[4*q+1] = -__expf(a.y);
      Av[4*q+2] = -__expf(a.z); Av[4*q+3] = -__expf(a.w);
    }
  }
  int rowbase = zb * LL + c * CLEN;
  const float4* Bp4 = reinterpret_cast<const float4*>(Bm + (size_t)rowbase * DS);
  float h[DS];
  #pragma unroll
  for (int n = 0; n < DS; n++) h[n] = 0.f;
  float sdt = 0.f;
  float dtv = dt[(size_t)rowbase * DI + d];
  float xv  = xc[(size_t)rowbase * DI + d];
  #pragma unroll 4
  for (int s = 0; s < CLEN; s++) {
    float dtn_ = 0.f, xn_ = 0.f;
    if (s + 1 < CLEN) {
      dtn_ = dt[(size_t)(rowbase + s + 1) * DI + d];
      xn_  = xc[(size_t)(rowbase + s + 1) * DI + d];
    }
    float4 B0 = Bp4[s*4+0], B1 = Bp4[s*4+1], B2 = Bp4[s*4+2], B3 = Bp4[s*4+3];
    float Bv[DS] = {B0.x,B0.y,B0.z,B0.w, B1.x,B1.y,B1.z,B1.w,
                    B2.x,B2.y,B2.z,B2.w, B3.x,B3.y,B3.z,B3.w};
    float dtx = dtv * xv;
    sdt += dtv;
    #pragma unroll
    for (int n = 0; n < DS; n++) {
      float dA = __expf(dtv * Av[n]);
      h[n] = __fmaf_rn(dA, h[n], dtx * Bv[n]);
    }
    dtv = dtn_; xv = xn_;
  }
  size_t base = ((size_t)(zb * NCH + c) * DI + d) * DS;
  float4* Sp = reinterpret_cast<float4*>(S + base);
  float4* Pp = reinterpret_cast<float4*>(P + base);
  #pragma unroll
  for (int q = 0; q < 4; q++) {
    Sp[q] = make_float4(h[4*q+0], h[4*q+1], h[4*q+2], h[4*q+3]);
    Pp[q] = make_float4(__expf(Av[4*q+0]*sdt), __expf(Av[4*q+1]*sdt),
                        __expf(Av[4*q+2]*sdt), __expf(Av[4*q+3]*sdt));
  }
}

// ---------------- S2: combine carries across chunks (in-place: S -> Hin) ---
__global__ __launch_bounds__(256) void k_scan2(
    float* __restrict__ S, const float* __restrict__ P) {
  int g = blockIdx.x * 256 + threadIdx.x;
  int zb = g / (DI * DS);
  int rem = g % (DI * DS);
  const int stride = DI * DS;
  size_t base = (size_t)zb * NCH * stride + rem;
  float carry = 0.f;
  for (int c0 = 0; c0 < NCH; c0 += 8) {
    float p8[8], s8[8];
    #pragma unroll
    for (int j = 0; j < 8; j++) {
      p8[j] = P[base + (size_t)(c0 + j) * stride];
      s8[j] = S[base + (size_t)(c0 + j) * stride];
    }
    #pragma unroll
    for (int j = 0; j < 8; j++) {
      S[base + (size_t)(c0 + j) * stride] = carry;
      carry = __fmaf_rn(p8[j], carry, s8[j]);
    }
  }
}

// ---------------- S3: final per-chunk scan + y ----------------
__global__ __launch_bounds__(128) void k_scan3(
    const float* __restrict__ dt, const float* __restrict__ xc,
    const float* __restrict__ Bm, const float* __restrict__ Cm,
    const float* __restrict__ z, const float* __restrict__ Hin,
    const float* __restrict__ Alf, const float* __restrict__ Alb,
    const float* __restrict__ Df, const float* __restrict__ Db,
    float* __restrict__ y) {
  int zb = blockIdx.z;
  int dir = zb >> 1, b = zb & 1;
  int d = blockIdx.x * 128 + threadIdx.x;
  int c = blockIdx.y;
  const float* Al = dir ? Alb : Alf;
  const float* Dp = dir ? Db : Df;
  float Av[DS];
  {
    const float4* ap = reinterpret_cast<const float4*>(Al + d * DS);
    #pragma unroll
    for (int q = 0; q < 4; q++) {
      float4 a = ap[q];
      Av[4*q+0] = -__expf(a.x); Av[4*q+1] = -__expf(a.y);
      Av[4*q+2] = -__expf(a.z); Av[4*q+3] = -__expf(a.w);
    }
  }
  float Dv = Dp[d];
  int rowbase = zb * LL + c * CLEN;
  const float4* Bp4 = reinterpret_cast<const float4*>(Bm + (size_t)rowbase * DS);
  const float4* Cp4 = reinterpret_cast<const float4*>(Cm + (size_t)rowbase * DS);
  size_t base = ((size_t)(zb * NCH + c) * DI + d) * DS;
  float h[DS];
  {
    const float4* hp = reinterpret_cast<const float4*>(Hin + base);
    #pragma unroll
    for (int q = 0; q < 4; q++) {
      float4 a = hp[q];
      h[4*q+0] = a.x; h[4*q+1] = a.y; h[4*q+2] = a.z; h[4*q+3] = a.w;
    }
  }
  float dtv = dt[(size_t)rowbase * DI + d];
  float xv  = xc[(size_t)rowbase * DI + d];
  #pragma unroll 4
  for (int s = 0; s < CLEN; s++) {
    float dtn_ = 0.f, xn_ = 0.f;
    if (s + 1 < CLEN) {
      dtn_ = dt[(size_t)(rowbase + s + 1) * DI + d];
      xn_  = xc[(size_t)(rowbase + s + 1) * DI + d];
    }
    float4 B0 = Bp4[s*4+0], B1 = Bp4[s*4+1], B2 = Bp4[s*4+2], B3 = Bp4[s*4+3];
    float Bv[DS] = {B0.x,B0.y,B0.z,B0.w, B1.x,B1.y,B1.z,B1.w,
                    B2.x,B2.y,B2.z,B2.w, B3.x,B3.y,B3.z,B3.w};
    float4 C0 = Cp4[s*4+0], C1 = Cp4[s*4+1], C2 = Cp4[s*4+2], C3 = Cp4[s*4+3];
    float Cv[DS] = {C0.x,C0.y,C0.z,C0.w, C1.x,C1.y,C1.z,C1.w,
                    C2.x,C2.y,C2.z,C2.w, C3.x,C3.y,C3.z,C3.w};
    float dtx = dtv * xv;
    float acc = xv * Dv;
    #pragma unroll
    for (int n = 0; n < DS; n++) {
      float dA = __expf(dtv * Av[n]);
      h[n] = __fmaf_rn(dA, h[n], dtx * Bv[n]);
      acc = __fmaf_rn(h[n], Cv[n], acc);
    }
    int sg = c * CLEN + s;
    int mr = b * LL + (dir ? (LL - 1 - sg) : sg);
    float zv = z[(size_t)mr * DI + d];
    y[(size_t)(rowbase + s) * DI + d] = acc * siluf(zv);
    dtv = dtn_; xv = xn_;
  }
}

// ---------------- K5: out_proj via MFMA (fused y_f + rev(y_b) + bf16 cvt) ---
// block 128 = 2 waves; tile 16 rows x 192 cols; wave w covers ng = w*6..w*6+5
__global__ __launch_bounds__(128) void k_outproj(
    const float* __restrict__ y, const unsigned short* __restrict__ bout,
    float* __restrict__ out) {
  int l = threadIdx.x & 63, w = threadIdx.x >> 6;
  int row0 = blockIdx.x * 16;
  int row = row0 + (l & 15);
  int b = row >> 11, ll = row & (LL - 1);
  const float* yf = y + (size_t)(b * LL + ll) * DI + (l >> 4) * 8;
  const float* yb = y + (size_t)((2 + b) * LL + (LL - 1 - ll)) * DI + (l >> 4) * 8;
  f32x4 acc[6];
  #pragma unroll
  for (int g = 0; g < 6; g++) acc[g] = (f32x4){0.f, 0.f, 0.f, 0.f};
  #pragma unroll
  for (int ks = 0; ks < 12; ks++) {
    const float4* yf4 = reinterpret_cast<const float4*>(yf + ks * 32);
    const float4* yb4 = reinterpret_cast<const float4*>(yb + ks * 32);
    float4 f0 = yf4[0], f1 = yf4[1];
    float4 g0 = yb4[0], g1 = yb4[1];
    bf16x8 a;
    a[0] = (short)f2bf(f0.x + g0.x); a[1] = (short)f2bf(f0.y + g0.y);
    a[2] = (short)f2bf(f0.z + g0.z); a[3] = (short)f2bf(f0.w + g0.w);
    a[4] = (short)f2bf(f1.x + g1.x); a[5] = (short)f2bf(f1.y + g1.y);
    a[6] = (short)f2bf(f1.z + g1.z); a[7] = (short)f2bf(f1.w + g1.w);
    #pragma unroll
    for (int g = 0; g < 6; g++) {
      int ng = w * 6 + g;
      bf16x8 bb = *reinterpret_cast<const bf16x8*>(bout + ((size_t)(ks * 12 + ng) * 64 + l) * 8);
      acc[g] = __builtin_amdgcn_mfma_f32_16x16x32_bf16(a, bb, acc[g], 0, 0, 0);
    }
  }
  int rbase = row0 + (l >> 4) * 4;
  #pragma unroll
  for (int g = 0; g < 6; g++) {
    int col = (w * 6 + g) * 16 + (l & 15);
    #pragma unroll
    for (int r = 0; r < 4; r++) out[(size_t)(rbase + r) * DM + col] = acc[g][r];
  }
}

extern "C" void kernel_launch(void* const* d_in, const int* in_sizes, int n_in,
                              void* d_out, int out_size, void* d_ws, size_t ws_size,
                              hipStream_t stream) {
  const float* hid  = (const float*)d_in[0];
  const float* res  = (const float*)d_in[1];
  const float* nw   = (const float*)d_in[2];
  const float* wip  = (const float*)d_in[3];
  const float* wop  = (const float*)d_in[4];
  const float* cwf  = (const float*)d_in[5];
  const float* cbf  = (const float*)d_in[6];
  const float* xpwf = (const float*)d_in[7];
  const float* dtwf = (const float*)d_in[8];
  const float* dtbf = (const float*)d_in[9];
  const float* Alf  = (const float*)d_in[10];
  const float* Df   = (const float*)d_in[11];
  const float* cwb  = (const float*)d_in[12];
  const float* cbb  = (const float*)d_in[13];
  const float* xpwb = (const float*)d_in[14];
  const float* dtwb = (const float*)d_in[15];
  const float* dtbb = (const float*)d_in[16];
  const float* Alb  = (const float*)d_in[17];
  const float* Db   = (const float*)d_in[18];

  float* out_p  = (float*)d_out;                  // (B,L,192)
  float* resid  = out_p + NROW * DM;              // (B,L,192)

  float* ws = (float*)d_ws;
  float* xh   = ws;                         // 1572864
  float* zz   = xh   + NROW * DI;           // 1572864
  float* xc   = zz   + NROW * DI;           // 3145728
  float* dt   = xc   + 2 * NROW * DI;       // 3145728
  float* Bm   = dt   + 2 * NROW * DI;       // 131072
  float* Cm   = Bm   + 2 * NROW * DS;       // 131072
  float* yy   = Cm   + 2 * NROW * DS;       // 3145728
  float* S    = yy   + 2 * NROW * DI;       // 1572864
  float* P    = S    + 2 * BB * NCH * DI * DS;  // 1572864
  float* xdbl = P    + 2 * BB * NCH * DI * DS;  // 524288
  float* wdt  = xdbl + 2 * NROW * 64;       // 9216
  float* fend = wdt  + N_DT;
  unsigned short* xnb = (unsigned short*)fend;            // 786432 ushort
  unsigned short* xcb = xnb + NROW * DM;                  // 3145728 ushort
  unsigned short* bin = xcb + 2 * NROW * DI;              // 147456
  unsigned short* bout = bin + N_BFIN;                    // 73728
  unsigned short* bxp  = bout + N_BFOUT;                  // 49152

  k_wprep<<<(N_PREP + 255) / 256, 256, 0, stream>>>(wip, wop, xpwf, xpwb, dtwf, dtwb,
                                                    bin, bout, bxp, wdt);
  k_rmsnorm<<<NROW / 4, 256, 0, stream>>>(hid, res, nw, resid, xnb);
  k_inproj<<<NROW / 16, 256, 0, stream>>>(xnb, bin, xh, zz);
  k_conv<<<dim3(NROW * DI / 256, 2), 256, 0, stream>>>(xh, cwf, cbf, cwb, cbb, xc, xcb);
  k_xpmm<<<dim3(NROW / 16, 2), 64, 0, stream>>>(xcb, bxp, xdbl);
  k_dtbc<<<2 * NROW, 128, 0, stream>>>(xdbl, wdt, dtbf, dtbb, dt, Bm, Cm);
  k_scan1<<<dim3(DI / 128, NCH, 2 * BB), 128, 0, stream>>>(dt, xc, Bm, Alf, Alb, S, P);
  k_scan2<<<(2 * BB * DI * DS) / 256, 256, 0, stream>>>(S, P);
  k_scan3<<<dim3(DI / 128, NCH, 2 * BB), 128, 0, stream>>>(dt, xc, Bm, Cm, zz, S,
                                                           Alf, Alb, Df, Db, yy);
  k_outproj<<<NROW / 16, 128, 0, stream>>>(yy, bout, out_p);
}

// Round 9
// 212.267 us; speedup vs baseline: 1.2256x; 1.1092x over previous
//
#include <hip/hip_runtime.h>
#include <math.h>

#define BB 2
#define LL 2048
#define DM 192
#define DI 384
#define DS 16
#define RK 12
#define NROW (BB*LL)      // 4096
#define NCH 64
#define CLEN (LL/NCH)     // 32

typedef __attribute__((ext_vector_type(8))) short bf16x8;
typedef __attribute__((ext_vector_type(4))) float f32x4;

__device__ __forceinline__ float siluf(float v) { return v / (1.f + __expf(-v)); }

__device__ __forceinline__ unsigned short f2bf(float f) {
  unsigned int x = __float_as_uint(f);
  unsigned int r = (x + 0x7fffu + ((x >> 16) & 1u)) >> 16;
  return (unsigned short)r;
}
__device__ __forceinline__ float bf2f(unsigned short u) {
  return __uint_as_float(((unsigned int)u) << 16);
}

// ---------------- K0: pack weights into MFMA fragment order (bf16) ----------
// bin : [6 ks][48 ng][64 l][8 j]  = bf16(in_proj_w[c][k]), c=ng*16+(l&15), k=ks*32+(l>>4)*8+j
// bout: [12][12][64][8]           = bf16(out_proj_w[c][k])
// bxp : [dir][12][4][64][8]       = bf16(x_proj_w[e][k]) (e>=44 -> 0)
// wdt : [dir][12][384] f32        = dt_w[d][j]
#define N_BFIN  (6*48*512)      // 147456
#define N_BFOUT (12*12*512)     // 73728
#define N_BFXP  (2*12*4*512)    // 49152
#define N_DT    (2*RK*DI)       // 9216
#define N_PREP  (N_BFIN + N_BFOUT + N_BFXP + N_DT)

__global__ __launch_bounds__(256) void k_wprep(
    const float* __restrict__ wip, const float* __restrict__ wop,
    const float* __restrict__ xpwf, const float* __restrict__ xpwb,
    const float* __restrict__ dtwf, const float* __restrict__ dtwb,
    unsigned short* __restrict__ bin, unsigned short* __restrict__ bout,
    unsigned short* __restrict__ bxp, float* __restrict__ wdt) {
  int i = blockIdx.x * 256 + threadIdx.x;
  if (i < N_BFIN) {
    int j = i & 7, l = (i >> 3) & 63, ng = (i >> 9) % 48, ks = i / (48 * 512);
    int k = ks * 32 + (l >> 4) * 8 + j, c = ng * 16 + (l & 15);
    bin[i] = f2bf(wip[c * DM + k]);
  } else if (i < N_BFIN + N_BFOUT) {
    int t = i - N_BFIN;
    int j = t & 7, l = (t >> 3) & 63, ng = (t >> 9) % 12, ks = t / (12 * 512);
    int k = ks * 32 + (l >> 4) * 8 + j, c = ng * 16 + (l & 15);
    bout[t] = f2bf(wop[c * DI + k]);
  } else if (i < N_BFIN + N_BFOUT + N_BFXP) {
    int t = i - N_BFIN - N_BFOUT;
    int j = t & 7, l = (t >> 3) & 63, ng = (t >> 9) & 3, ks = (t >> 11) % 12;
    int dir = t / (12 * 4 * 512);
    int k = ks * 32 + (l >> 4) * 8 + j, e = ng * 16 + (l & 15);
    const float* src = dir ? xpwb : xpwf;
    bxp[t] = (e < RK + 2 * DS) ? f2bf(src[e * DI + k]) : (unsigned short)0;
  } else if (i < N_PREP) {
    int t = i - N_BFIN - N_BFOUT - N_BFXP;
    int dir = t / (RK * DI), rem = t % (RK * DI);
    int j = rem / DI, d = rem % DI;
    const float* src = dir ? dtwb : dtwf;
    wdt[t] = src[d * RK + j];
  }
}

// ---------------- K1: residual add + RMSNorm -> bf16 xnb ----------------
__global__ __launch_bounds__(256) void k_rmsnorm(
    const float* __restrict__ h, const float* __restrict__ r,
    const float* __restrict__ w, float* __restrict__ res,
    unsigned short* __restrict__ xnb) {
  int row = blockIdx.x * 4 + (threadIdx.x >> 6);
  int lane = threadIdx.x & 63;
  const float* hp = h + row * DM;
  const float* rp = r + row * DM;
  float v0 = hp[lane]       + rp[lane];
  float v1 = hp[lane + 64]  + rp[lane + 64];
  float v2 = hp[lane + 128] + rp[lane + 128];
  float ss = v0 * v0 + v1 * v1 + v2 * v2;
  #pragma unroll
  for (int o = 32; o; o >>= 1) ss += __shfl_xor(ss, o);
  float inv = rsqrtf(ss * (1.f / DM) + 1e-5f);
  float* rr = res + row * DM;
  unsigned short* xo = xnb + row * DM;
  rr[lane] = v0; rr[lane + 64] = v1; rr[lane + 128] = v2;
  xo[lane]       = f2bf(v0 * inv * w[lane]);
  xo[lane + 64]  = f2bf(v1 * inv * w[lane + 64]);
  xo[lane + 128] = f2bf(v2 * inv * w[lane + 128]);
}

// ---------------- K2: in_proj via MFMA -> bf16 xhb, zb ----------------
// grid (256 rowtiles, 12 ng-quads), block 64 = 1 wave; 12 waves/CU
__global__ __launch_bounds__(64) void k_inproj(
    const unsigned short* __restrict__ xnb, const unsigned short* __restrict__ bin,
    unsigned short* __restrict__ xhb, unsigned short* __restrict__ zb) {
  int l = threadIdx.x;
  int row0 = blockIdx.x * 16;
  int ng0 = blockIdx.y * 4;
  const unsigned short* arow = xnb + (size_t)(row0 + (l & 15)) * DM + ((l >> 4) * 8);
  f32x4 acc[4];
  #pragma unroll
  for (int g = 0; g < 4; g++) acc[g] = (f32x4){0.f, 0.f, 0.f, 0.f};
  #pragma unroll
  for (int ks = 0; ks < 6; ks++) {
    bf16x8 a = *reinterpret_cast<const bf16x8*>(arow + ks * 32);
    #pragma unroll
    for (int g = 0; g < 4; g++) {
      bf16x8 b = *reinterpret_cast<const bf16x8*>(bin + ((size_t)(ks * 48 + ng0 + g) * 64 + l) * 8);
      acc[g] = __builtin_amdgcn_mfma_f32_16x16x32_bf16(a, b, acc[g], 0, 0, 0);
    }
  }
  int rbase = row0 + (l >> 4) * 4;
  #pragma unroll
  for (int g = 0; g < 4; g++) {
    int col = (ng0 + g) * 16 + (l & 15);
    unsigned short* dst = (col < DI) ? (xhb + col) : (zb + (col - DI));
    #pragma unroll
    for (int r = 0; r < 4; r++) dst[(size_t)(rbase + r) * DI] = f2bf(acc[g][r]);
  }
}

// ---------------- K3: causal depthwise conv + SiLU -> bf16 xcb ----------
__global__ __launch_bounds__(256) void k_conv(
    const unsigned short* __restrict__ xhb,
    const float* __restrict__ cwf, const float* __restrict__ cbf,
    const float* __restrict__ cwb, const float* __restrict__ cbb,
    unsigned short* __restrict__ xcb) {
  int dir = blockIdx.y;
  int g = blockIdx.x * 256 + threadIdx.x;
  int row = g / DI, d = g % DI;
  int b = row >> 11, s = row & (LL - 1);
  const float* cw = dir ? cwb : cwf;
  const float* cb = dir ? cbb : cbf;
  float acc = cb[d];
  #pragma unroll
  for (int k = 0; k < 4; k++) {
    int sp = s - 3 + k;
    if (sp >= 0) {
      int mr = b * LL + (dir ? (LL - 1 - sp) : sp);
      acc += cw[d * 4 + k] * bf2f(xhb[(size_t)mr * DI + d]);
    }
  }
  xcb[(size_t)(dir * NROW + row) * DI + d] = f2bf(siluf(acc));
}

// ---------------- K4: x_proj MFMA + dt/B/C fused ----------------
// grid (256 rowtiles, 2 dirs), block 128 = 2 waves; wave w: ng = w*2..w*2+1
__global__ __launch_bounds__(128) void k_xpmm(
    const unsigned short* __restrict__ xcb, const unsigned short* __restrict__ bxp,
    const float* __restrict__ wdt_all,
    const float* __restrict__ dtbf, const float* __restrict__ dtbb,
    float* __restrict__ dt, float* __restrict__ Bm, float* __restrict__ Cm) {
  __shared__ float xd[16][48];
  int l = threadIdx.x & 63, w = threadIdx.x >> 6;
  int dir = blockIdx.y;
  int row0 = blockIdx.x * 16;
  const unsigned short* arow = xcb + (size_t)(dir * NROW + row0 + (l & 15)) * DI + ((l >> 4) * 8);
  const unsigned short* wb = bxp + (size_t)dir * 12 * 4 * 512;
  f32x4 acc[2];
  acc[0] = (f32x4){0.f, 0.f, 0.f, 0.f};
  acc[1] = (f32x4){0.f, 0.f, 0.f, 0.f};
  #pragma unroll
  for (int ks = 0; ks < 12; ks++) {
    bf16x8 a = *reinterpret_cast<const bf16x8*>(arow + ks * 32);
    #pragma unroll
    for (int g = 0; g < 2; g++) {
      int ng = w * 2 + g;
      bf16x8 b = *reinterpret_cast<const bf16x8*>(wb + ((size_t)(ks * 4 + ng) * 64 + l) * 8);
      acc[g] = __builtin_amdgcn_mfma_f32_16x16x32_bf16(a, b, acc[g], 0, 0, 0);
    }
  }
  int rbase = (l >> 4) * 4;
  #pragma unroll
  for (int g = 0; g < 2; g++) {
    int col = (w * 2 + g) * 16 + (l & 15);
    #pragma unroll
    for (int r = 0; r < 4; r++) xd[rbase + r][col] = acc[g][r];
  }
  __syncthreads();
  const float* wdt = wdt_all + dir * RK * DI;
  const float* dtb = dir ? dtbb : dtbf;
  int t = threadIdx.x;
  // dt: 16 rows x 384 = 6144 outputs, 48 per thread, coalesced in d
  #pragma unroll
  for (int i = 0; i < 48; i++) {
    int idx = i * 128 + t;
    int row = idx / DI, d = idx % DI;
    float a = dtb[d];
    #pragma unroll
    for (int j = 0; j < RK; j++) a = __fmaf_rn(xd[row][j], wdt[j * DI + d], a);
    a = (a > 20.f) ? a : log1pf(__expf(a));
    dt[(size_t)(dir * NROW + row0 + row) * DI + d] = a;
  }
  // B/C: 16 rows x 32
  #pragma unroll
  for (int i = 0; i < 4; i++) {
    int idx = i * 128 + t;
    int row = idx / 32, j = idx % 32;
    float v = xd[row][RK + j];
    if (j < DS) Bm[(size_t)(dir * NROW + row0 + row) * DS + j] = v;
    else        Cm[(size_t)(dir * NROW + row0 + row) * DS + (j - DS)] = v;
  }
}

// ---------------- S1: per-chunk local scan aggregates ----------------
__global__ __launch_bounds__(128) void k_scan1(
    const float* __restrict__ dt, const unsigned short* __restrict__ xcb,
    const float* __restrict__ Bm,
    const float* __restrict__ Alf, const float* __restrict__ Alb,
    float* __restrict__ S, float* __restrict__ P) {
  int zb = blockIdx.z;
  int dir = zb >> 1;
  int d = blockIdx.x * 128 + threadIdx.x;
  int c = blockIdx.y;
  const float* Al = dir ? Alb : Alf;
  float Av[DS];
  {
    const float4* ap = reinterpret_cast<const float4*>(Al + d * DS);
    #pragma unroll
    for (int q = 0; q < 4; q++) {
      float4 a = ap[q];
      Av[4*q+0] = -__expf(a.x); Av[4*q+1] = -__expf(a.y);
      Av[4*q+2] = -__expf(a.z); Av[4*q+3] = -__expf(a.w);
    }
  }
  int rowbase = zb * LL + c * CLEN;
  const float4* Bp4 = reinterpret_cast<const float4*>(Bm + (size_t)rowbase * DS);
  float h[DS];
  #pragma unroll
  for (int n = 0; n < DS; n++) h[n] = 0.f;
  float sdt = 0.f;
  float dtv = dt[(size_t)rowbase * DI + d];
  float xv  = bf2f(xcb[(size_t)rowbase * DI + d]);
  #pragma unroll 4
  for (int s = 0; s < CLEN; s++) {
    float dtn_ = 0.f, xn_ = 0.f;
    if (s + 1 < CLEN) {
      dtn_ = dt[(size_t)(rowbase + s + 1) * DI + d];
      xn_  = bf2f(xcb[(size_t)(rowbase + s + 1) * DI + d]);
    }
    float4 B0 = Bp4[s*4+0], B1 = Bp4[s*4+1], B2 = Bp4[s*4+2], B3 = Bp4[s*4+3];
    float Bv[DS] = {B0.x,B0.y,B0.z,B0.w, B1.x,B1.y,B1.z,B1.w,
                    B2.x,B2.y,B2.z,B2.w, B3.x,B3.y,B3.z,B3.w};
    float dtx = dtv * xv;
    sdt += dtv;
    #pragma unroll
    for (int n = 0; n < DS; n++) {
      float dA = __expf(dtv * Av[n]);
      h[n] = __fmaf_rn(dA, h[n], dtx * Bv[n]);
    }
    dtv = dtn_; xv = xn_;
  }
  size_t base = ((size_t)(zb * NCH + c) * DI + d) * DS;
  float4* Sp = reinterpret_cast<float4*>(S + base);
  float4* Pp = reinterpret_cast<float4*>(P + base);
  #pragma unroll
  for (int q = 0; q < 4; q++) {
    Sp[q] = make_float4(h[4*q+0], h[4*q+1], h[4*q+2], h[4*q+3]);
    Pp[q] = make_float4(__expf(Av[4*q+0]*sdt), __expf(Av[4*q+1]*sdt),
                        __expf(Av[4*q+2]*sdt), __expf(Av[4*q+3]*sdt));
  }
}

// ---------------- S2: combine carries across chunks (in-place: S -> Hin) ---
__global__ __launch_bounds__(256) void k_scan2(
    float* __restrict__ S, const float* __restrict__ P) {
  int g = blockIdx.x * 256 + threadIdx.x;
  int zb = g / (DI * DS);
  int rem = g % (DI * DS);
  const int stride = DI * DS;
  size_t base = (size_t)zb * NCH * stride + rem;
  float carry = 0.f;
  for (int c0 = 0; c0 < NCH; c0 += 8) {
    float p8[8], s8[8];
    #pragma unroll
    for (int j = 0; j < 8; j++) {
      p8[j] = P[base + (size_t)(c0 + j) * stride];
      s8[j] = S[base + (size_t)(c0 + j) * stride];
    }
    #pragma unroll
    for (int j = 0; j < 8; j++) {
      S[base + (size_t)(c0 + j) * stride] = carry;
      carry = __fmaf_rn(p8[j], carry, s8[j]);
    }
  }
}

// ---------------- S3: final per-chunk scan + y (bf16 out) ----------------
__global__ __launch_bounds__(128) void k_scan3(
    const float* __restrict__ dt, const unsigned short* __restrict__ xcb,
    const float* __restrict__ Bm, const float* __restrict__ Cm,
    const unsigned short* __restrict__ zb_, const float* __restrict__ Hin,
    const float* __restrict__ Alf, const float* __restrict__ Alb,
    const float* __restrict__ Df, const float* __restrict__ Db,
    unsigned short* __restrict__ yb) {
  int zbi = blockIdx.z;
  int dir = zbi >> 1, b = zbi & 1;
  int d = blockIdx.x * 128 + threadIdx.x;
  int c = blockIdx.y;
  const float* Al = dir ? Alb : Alf;
  const float* Dp = dir ? Db : Df;
  float Av[DS];
  {
    const float4* ap = reinterpret_cast<const float4*>(Al + d * DS);
    #pragma unroll
    for (int q = 0; q < 4; q++) {
      float4 a = ap[q];
      Av[4*q+0] = -__expf(a.x); Av[4*q+1] = -__expf(a.y);
      Av[4*q+2] = -__expf(a.z); Av[4*q+3] = -__expf(a.w);
    }
  }
  float Dv = Dp[d];
  int rowbase = zbi * LL + c * CLEN;
  const float4* Bp4 = reinterpret_cast<const float4*>(Bm + (size_t)rowbase * DS);
  const float4* Cp4 = reinterpret_cast<const float4*>(Cm + (size_t)rowbase * DS);
  size_t base = ((size_t)(zbi * NCH + c) * DI + d) * DS;
  float h[DS];
  {
    const float4* hp = reinterpret_cast<const float4*>(Hin + base);
    #pragma unroll
    for (int q = 0; q < 4; q++) {
      float4 a = hp[q];
      h[4*q+0] = a.x; h[4*q+1] = a.y; h[4*q+2] = a.z; h[4*q+3] = a.w;
    }
  }
  float dtv = dt[(size_t)rowbase * DI + d];
  float xv  = bf2f(xcb[(size_t)rowbase * DI + d]);
  #pragma unroll 4
  for (int s = 0; s < CLEN; s++) {
    float dtn_ = 0.f, xn_ = 0.f;
    if (s + 1 < CLEN) {
      dtn_ = dt[(size_t)(rowbase + s + 1) * DI + d];
      xn_  = bf2f(xcb[(size_t)(rowbase + s + 1) * DI + d]);
    }
    float4 B0 = Bp4[s*4+0], B1 = Bp4[s*4+1], B2 = Bp4[s*4+2], B3 = Bp4[s*4+3];
    float Bv[DS] = {B0.x,B0.y,B0.z,B0.w, B1.x,B1.y,B1.z,B1.w,
                    B2.x,B2.y,B2.z,B2.w, B3.x,B3.y,B3.z,B3.w};
    float4 C0 = Cp4[s*4+0], C1 = Cp4[s*4+1], C2 = Cp4[s*4+2], C3 = Cp4[s*4+3];
    float Cv[DS] = {C0.x,C0.y,C0.z,C0.w, C1.x,C1.y,C1.z,C1.w,
                    C2.x,C2.y,C2.z,C2.w, C3.x,C3.y,C3.z,C3.w};
    float dtx = dtv * xv;
    float acc = xv * Dv;
    #pragma unroll
    for (int n = 0; n < DS; n++) {
      float dA = __expf(dtv * Av[n]);
      h[n] = __fmaf_rn(dA, h[n], dtx * Bv[n]);
      acc = __fmaf_rn(h[n], Cv[n], acc);
    }
    int sg = c * CLEN + s;
    int mr = b * LL + (dir ? (LL - 1 - sg) : sg);
    float zv = bf2f(zb_[(size_t)mr * DI + d]);
    yb[(size_t)(rowbase + s) * DI + d] = f2bf(acc * siluf(zv));
    dtv = dtn_; xv = xn_;
  }
}

// ---------------- K5: out_proj via MFMA (fused y_f + rev(y_b)) ---------
// grid (256 rowtiles, 6 ng-pairs), block 64 = 1 wave
__global__ __launch_bounds__(64) void k_outproj(
    const unsigned short* __restrict__ yb, const unsigned short* __restrict__ bout,
    float* __restrict__ out) {
  int l = threadIdx.x;
  int row0 = blockIdx.x * 16;
  int ng0 = blockIdx.y * 2;
  int row = row0 + (l & 15);
  int b = row >> 11, ll = row & (LL - 1);
  const unsigned short* yf = yb + (size_t)(b * LL + ll) * DI + (l >> 4) * 8;
  const unsigned short* yr = yb + (size_t)((2 + b) * LL + (LL - 1 - ll)) * DI + (l >> 4) * 8;
  f32x4 acc[2];
  acc[0] = (f32x4){0.f, 0.f, 0.f, 0.f};
  acc[1] = (f32x4){0.f, 0.f, 0.f, 0.f};
  #pragma unroll
  for (int ks = 0; ks < 12; ks++) {
    bf16x8 f8 = *reinterpret_cast<const bf16x8*>(yf + ks * 32);
    bf16x8 g8 = *reinterpret_cast<const bf16x8*>(yr + ks * 32);
    bf16x8 a;
    #pragma unroll
    for (int j = 0; j < 8; j++)
      a[j] = (short)f2bf(bf2f((unsigned short)f8[j]) + bf2f((unsigned short)g8[j]));
    #pragma unroll
    for (int g = 0; g < 2; g++) {
      bf16x8 bb = *reinterpret_cast<const bf16x8*>(bout + ((size_t)(ks * 12 + ng0 + g) * 64 + l) * 8);
      acc[g] = __builtin_amdgcn_mfma_f32_16x16x32_bf16(a, bb, acc[g], 0, 0, 0);
    }
  }
  int rbase = row0 + (l >> 4) * 4;
  #pragma unroll
  for (int g = 0; g < 2; g++) {
    int col = (ng0 + g) * 16 + (l & 15);
    #pragma unroll
    for (int r = 0; r < 4; r++) out[(size_t)(rbase + r) * DM + col] = acc[g][r];
  }
}

extern "C" void kernel_launch(void* const* d_in, const int* in_sizes, int n_in,
                              void* d_out, int out_size, void* d_ws, size_t ws_size,
                              hipStream_t stream) {
  const float* hid  = (const float*)d_in[0];
  const float* res  = (const float*)d_in[1];
  const float* nw   = (const float*)d_in[2];
  const float* wip  = (const float*)d_in[3];
  const float* wop  = (const float*)d_in[4];
  const float* cwf  = (const float*)d_in[5];
  const float* cbf  = (const float*)d_in[6];
  const float* xpwf = (const float*)d_in[7];
  const float* dtwf = (const float*)d_in[8];
  const float* dtbf = (const float*)d_in[9];
  const float* Alf  = (const float*)d_in[10];
  const float* Df   = (const float*)d_in[11];
  const float* cwb  = (const float*)d_in[12];
  const float* cbb  = (const float*)d_in[13];
  const float* xpwb = (const float*)d_in[14];
  const float* dtwb = (const float*)d_in[15];
  const float* dtbb = (const float*)d_in[16];
  const float* Alb  = (const float*)d_in[17];
  const float* Db   = (const float*)d_in[18];

  float* out_p  = (float*)d_out;                  // (B,L,192)
  float* resid  = out_p + NROW * DM;              // (B,L,192)

  float* ws = (float*)d_ws;
  // f32 arrays first
  float* dt   = ws;                          // 2*NROW*DI       = 3145728
  float* Bm   = dt   + 2 * NROW * DI;        // 131072
  float* Cm   = Bm   + 2 * NROW * DS;        // 131072
  float* S    = Cm   + 2 * NROW * DS;        // 1572864
  float* P    = S    + 2 * BB * NCH * DI * DS;  // 1572864
  float* wdt  = P    + 2 * BB * NCH * DI * DS;  // 9216
  // bf16 arrays
  unsigned short* xnb = (unsigned short*)(wdt + N_DT);   // NROW*DM
  unsigned short* xhb = xnb + NROW * DM;                 // NROW*DI
  unsigned short* zb  = xhb + NROW * DI;                 // NROW*DI
  unsigned short* xcb = zb  + NROW * DI;                 // 2*NROW*DI
  unsigned short* yb  = xcb + 2 * NROW * DI;             // 2*NROW*DI
  unsigned short* bin = yb  + 2 * NROW * DI;             // N_BFIN
  unsigned short* bout = bin + N_BFIN;                   // N_BFOUT
  unsigned short* bxp  = bout + N_BFOUT;                 // N_BFXP

  k_wprep<<<(N_PREP + 255) / 256, 256, 0, stream>>>(wip, wop, xpwf, xpwb, dtwf, dtwb,
                                                    bin, bout, bxp, wdt);
  k_rmsnorm<<<NROW / 4, 256, 0, stream>>>(hid, res, nw, resid, xnb);
  k_inproj<<<dim3(NROW / 16, 12), 64, 0, stream>>>(xnb, bin, xhb, zb);
  k_conv<<<dim3(NROW * DI / 256, 2), 256, 0, stream>>>(xhb, cwf, cbf, cwb, cbb, xcb);
  k_xpmm<<<dim3(NROW / 16, 2), 128, 0, stream>>>(xcb, bxp, wdt, dtbf, dtbb, dt, Bm, Cm);
  k_scan1<<<dim3(DI / 128, NCH, 2 * BB), 128, 0, stream>>>(dt, xcb, Bm, Alf, Alb, S, P);
  k_scan2<<<(2 * BB * DI * DS) / 256, 256, 0, stream>>>(S, P);
  k_scan3<<<dim3(DI / 128, NCH, 2 * BB), 128, 0, stream>>>(dt, xcb, Bm, Cm, zb, S,
                                                           Alf, Alb, Df, Db, yb);
  k_outproj<<<dim3(NROW / 16, 6), 64, 0, stream>>>(yb, bout, out_p);
}